// Round 10
// baseline (803.415 us; speedup 1.0000x reference)
//
#include <hip/hip_runtime.h>
#include <hip/hip_bf16.h>
#include <stdint.h>

#define SEQ   2048
#define DIN   5
#define HID   64
#define DTC   0.1f
#define BCOLS 8      // real batch columns per block (half-filled MFMA tile)
#define NWAVE 4

typedef __attribute__((ext_vector_type(8))) __bf16  bf16x8;
typedef __attribute__((ext_vector_type(8))) short   short8;
typedef __attribute__((ext_vector_type(4))) float   f32x4;
typedef __attribute__((ext_vector_type(4))) int     i32x4;
typedef __attribute__((ext_vector_type(2))) int     i32x2;
typedef unsigned long long u64;

__device__ __forceinline__ unsigned short f2bf(float f) {
    unsigned int u = __builtin_bit_cast(unsigned int, f);
    return (unsigned short)((u + 0x7FFFu + ((u >> 16) & 1u)) >> 16);  // RNE
}

__device__ __forceinline__ float fast_tanh(float x) {
    float e = __expf(2.0f * x);                       // saturates correctly at +-1
    return 1.0f - 2.0f * __builtin_amdgcn_rcpf(e + 1.0f);
}

__device__ __forceinline__ unsigned int cvt_pk_bf16(float lo, float hi) {
    unsigned int r;
    asm("v_cvt_pk_bf16_f32 %0, %1, %2" : "=v"(r) : "v"(lo), "v"(hi));
    return r;
}

// r9 structure, but 512 blocks x 8 REAL batch cols -> 2 co-resident blocks
// per CU with INDEPENDENT barriers. When one block stalls in its
// barrier/ds_read chain, the partner block's waves issue — TLP without the
// r7 shared-barrier lockstep. Lanes 8-15 duplicate lane (ln&7)'s x/tanh, so
// MFMA cols 8-15 compute never-stored duplicates; cols 0-7 are bit-identical
// to r9. Step body / LDS layout / soft barrier verbatim from r9.
__global__ __launch_bounds__(256) void ltc_kernel(
    const float* __restrict__ x,
    const float* __restrict__ tau,
    const float* __restrict__ Wih,
    const float* __restrict__ bih,
    const float* __restrict__ Whh,
    const float* __restrict__ bhh,
    const float* __restrict__ outw,
    const float* __restrict__ outb,
    float* __restrict__ out)
{
    const int tid  = threadIdx.x;
    const int wave = tid >> 6;
    const int lane = tid & 63;
    const int lg   = lane >> 4;
    const int ln   = lane & 15;
    const int b0   = blockIdx.x * BCOLS;

    __shared__ __align__(16) unsigned short sbuf[2][1024];  // 2 x 2KB fragment buffers
    __shared__ float redbuf[NWAVE][4][16];

    const int jbase = 16 * wave + 4 * lg;   // first C/D row (hidden idx) of this lane
    const int arow  = 16 * wave + ln;       // A-fragment row (hidden idx)

    float a[4], ow[4];
#pragma unroll
    for (int r = 0; r < 4; ++r) {
        a[r]  = 1.0f - DTC / fabsf(tau[jbase + r]);
        ow[r] = outw[jbase + r];
    }

    // A fragments: lane l holds A[l&15][(l>>4)*8 + q]  (verified r2/r3/r7/r9)
    short8 s0 = {0,0,0,0,0,0,0,0}, s1 = {0,0,0,0,0,0,0,0}, s2 = {0,0,0,0,0,0,0,0};
#pragma unroll
    for (int q = 0; q < 8; ++q) {
        s0[q] = (short)f2bf(DTC * Whh[arow * HID + lg * 8 + q]);
        s1[q] = (short)f2bf(DTC * Whh[arow * HID + 32 + lg * 8 + q]);
    }
    if (lg == 0) {
#pragma unroll
        for (int d = 0; d < DIN; ++d) s2[d] = (short)f2bf(DTC * Wih[arow * DIN + d]);
        s2[5] = (short)f2bf(DTC * (bih[arow] + bhh[arow]));
    }
    const bf16x8 Ahh0 = __builtin_bit_cast(bf16x8, s0);
    const bf16x8 Ahh1 = __builtin_bit_cast(bf16x8, s1);
    const bf16x8 Aix  = __builtin_bit_cast(bf16x8, s2);

    // write slot (fragment-linear): rows jbase..jbase+3, col ln
    const int wbyte = ((jbase >= 32) ? 1024 : 0) + (((jbase & 31) >> 3) * 256)
                    + ln * 16 + (((jbase >> 2) & 1) * 8);
    char* const wp0 = (char*)sbuf[0] + wbyte;
    char* const wp1 = (char*)sbuf[1] + wbyte;
    const char* const rp0 = (const char*)sbuf[0] + lane * 16;
    const char* const rp1 = (const char*)sbuf[1] + lane * 16;

    // zero parity-1 buffer (read at t=0: tanh(h0)=0)
    ((u64*)sbuf[1])[tid] = 0ULL;

    // x: per-lane row (lanes 8-15 duplicate ln&7), 8-step float4 groups
    const float* xb = x + (size_t)(b0 + (ln & 7)) * (SEQ * DIN);
    f32x4 bufA[10], bufB[10];
#pragma unroll
    for (int i = 0; i < 10; ++i) bufA[i] = *(const f32x4*)(xb + 4 * i);  // steps 0..7

    f32x4 h = {0.f, 0.f, 0.f, 0.f};

    // soft barrier: order LDS writes cross-wave; do NOT drain vmcnt
#define SBAR() asm volatile("s_waitcnt lgkmcnt(0)\n\ts_barrier" ::: "memory")

#define BODY(PAR, X0, X1, X2, X3, X4)                                              \
    {                                                                              \
        const char* rb = (PAR) ? rp0 : rp1;        /* read parity = !PAR */        \
        i32x4 r0 = *(const i32x4*)(rb);                                            \
        i32x4 r1 = *(const i32x4*)(rb + 1024);                                     \
        i32x4 bx;                                                                  \
        bx[0] = (int)cvt_pk_bf16(X0, X1);                                          \
        bx[1] = (int)cvt_pk_bf16(X2, X3);                                          \
        bx[2] = (int)cvt_pk_bf16(X4, 1.0f);                                        \
        bx[3] = 0;                                                                 \
        f32x4 c;                                                                   \
        c[0] = a[0]*h[0]; c[1] = a[1]*h[1]; c[2] = a[2]*h[2]; c[3] = a[3]*h[3];    \
        c = __builtin_amdgcn_mfma_f32_16x16x32_bf16(Aix,  __builtin_bit_cast(bf16x8, bx), c, 0, 0, 0); \
        c = __builtin_amdgcn_mfma_f32_16x16x32_bf16(Ahh0, __builtin_bit_cast(bf16x8, r0), c, 0, 0, 0); \
        c = __builtin_amdgcn_mfma_f32_16x16x32_bf16(Ahh1, __builtin_bit_cast(bf16x8, r1), c, 0, 0, 0); \
        h = c;                                                                     \
        float t0 = fast_tanh(c[0]), t1 = fast_tanh(c[1]);                          \
        float t2 = fast_tanh(c[2]), t3 = fast_tanh(c[3]);                          \
        i32x2 w; w[0] = (int)cvt_pk_bf16(t0, t1); w[1] = (int)cvt_pk_bf16(t2, t3); \
        *(i32x2*)((PAR) ? wp1 : wp0) = w;                                          \
    }

    // 8 steps per superstep; x-floats for step s are elements [5s..5s+4]
#define SUPER(BUF, DO_LOAD, LBUF, LOFF)                                            \
    SBAR();                                                                        \
    if (DO_LOAD) {                                                                 \
        _Pragma("unroll")                                                          \
        for (int i = 0; i < 10; ++i) LBUF[i] = *(const f32x4*)(xb + (LOFF) + 4*i); \
    }                                                                              \
    BODY(0, BUF[0][0], BUF[0][1], BUF[0][2], BUF[0][3], BUF[1][0])                 \
    SBAR(); BODY(1, BUF[1][1], BUF[1][2], BUF[1][3], BUF[2][0], BUF[2][1])         \
    SBAR(); BODY(0, BUF[2][2], BUF[2][3], BUF[3][0], BUF[3][1], BUF[3][2])         \
    SBAR(); BODY(1, BUF[3][3], BUF[4][0], BUF[4][1], BUF[4][2], BUF[4][3])         \
    SBAR(); BODY(0, BUF[5][0], BUF[5][1], BUF[5][2], BUF[5][3], BUF[6][0])         \
    SBAR(); BODY(1, BUF[6][1], BUF[6][2], BUF[6][3], BUF[7][0], BUF[7][1])         \
    SBAR(); BODY(0, BUF[7][2], BUF[7][3], BUF[8][0], BUF[8][1], BUF[8][2])         \
    SBAR(); BODY(1, BUF[8][3], BUF[9][0], BUF[9][1], BUF[9][2], BUF[9][3])

    for (int it = 0; it < SEQ / 16; ++it) {
        SUPER(bufA, true,            bufB, (it * 16 + 8)  * DIN)   // steps 16it..+7
        SUPER(bufB, it != SEQ/16 - 1, bufA, (it * 16 + 16) * DIN)  // steps 16it+8..+15
    }
#undef SUPER
#undef BODY
#undef SBAR

    // epilogue: out[b] = tanh(h_final) . out_w + out_b  (cols 0..7 only)
    float part = fast_tanh(h[0]) * ow[0] + fast_tanh(h[1]) * ow[1]
               + fast_tanh(h[2]) * ow[2] + fast_tanh(h[3]) * ow[3];
    redbuf[wave][lg][ln] = part;
    __syncthreads();
    if (tid < BCOLS) {
        float s = outb[0];
#pragma unroll
        for (int w = 0; w < NWAVE; ++w)
#pragma unroll
            for (int g = 0; g < 4; ++g) s += redbuf[w][g][tid];
        out[b0 + tid] = s;
    }
}

extern "C" void kernel_launch(void* const* d_in, const int* in_sizes, int n_in,
                              void* d_out, int out_size, void* d_ws, size_t ws_size,
                              hipStream_t stream) {
    const float* x    = (const float*)d_in[0];
    const float* tau  = (const float*)d_in[1];
    const float* Wih  = (const float*)d_in[2];
    const float* bih  = (const float*)d_in[3];
    const float* Whh  = (const float*)d_in[4];
    const float* bhh  = (const float*)d_in[5];
    const float* outw = (const float*)d_in[6];
    const float* outb = (const float*)d_in[7];
    float* out = (float*)d_out;

    const int batch = in_sizes[0] / (SEQ * DIN);   // 4096
    ltc_kernel<<<batch / BCOLS, NWAVE * 64, 0, stream>>>(x, tau, Wih, bih, Whh, bhh, outw, outb, out);
}

// Round 11
// 631.856 us; speedup vs baseline: 1.2715x; 1.2715x over previous
//
#include <hip/hip_runtime.h>
#include <hip/hip_bf16.h>
#include <stdint.h>

#define SEQ   2048
#define DIN   5
#define HID   64
#define DTC   0.1f
#define BTILE 16
#define NWAVE 2      // 2 fat waves: wave w owns hidden rows [32w, 32w+32)

typedef __attribute__((ext_vector_type(8))) __bf16  bf16x8;
typedef __attribute__((ext_vector_type(8))) short   short8;
typedef __attribute__((ext_vector_type(4))) float   f32x4;
typedef __attribute__((ext_vector_type(4))) int     i32x4;
typedef __attribute__((ext_vector_type(2))) int     i32x2;
typedef unsigned long long u64;

__device__ __forceinline__ unsigned short f2bf(float f) {
    unsigned int u = __builtin_bit_cast(unsigned int, f);
    return (unsigned short)((u + 0x7FFFu + ((u >> 16) & 1u)) >> 16);  // RNE
}

__device__ __forceinline__ float fast_tanh(float x) {
    float e = __expf(2.0f * x);                       // saturates correctly at +-1
    return 1.0f - 2.0f * __builtin_amdgcn_rcpf(e + 1.0f);
}

__device__ __forceinline__ unsigned int cvt_pk_bf16(float lo, float hi) {
    unsigned int r;
    asm("v_cvt_pk_bf16_f32 %0, %1, %2" : "=v"(r) : "v"(lo), "v"(hi));
    return r;
}

// 256 blocks x 128 threads: TWO fat waves per block. Wave w owns hidden rows
// [32w,32w+32) = 2 M-tiles of 16; B-fragments (k=0..63) are SHARED across
// M-tiles, so LDS reads stay at 2x ds_read_b128 per wave per step.
// vs r9 (4 thin waves): halved post-barrier LDS-pipe serialization, cheaper
// 2-wave barrier, and the extra per-wave issue (2 x-MFMA + 4 h-MFMA + 8 tanh)
// fills the ds_read latency window instead of a rival wave's interference.
// LDS exchange double-buffered fragment-linear (verified layout); soft
// barrier (lgkmcnt only, no vmcnt drain); x loaded in 8-step float4 groups.
__global__ __launch_bounds__(128) void ltc_kernel(
    const float* __restrict__ x,
    const float* __restrict__ tau,
    const float* __restrict__ Wih,
    const float* __restrict__ bih,
    const float* __restrict__ Whh,
    const float* __restrict__ bhh,
    const float* __restrict__ outw,
    const float* __restrict__ outb,
    float* __restrict__ out)
{
    const int tid  = threadIdx.x;
    const int wave = tid >> 6;
    const int lane = tid & 63;
    const int lg   = lane >> 4;
    const int ln   = lane & 15;
    const int b0   = blockIdx.x * BTILE;

    __shared__ __align__(16) unsigned short sbuf[2][1024];  // 2 x 2KB fragment buffers
    __shared__ float redbuf[NWAVE][4][BTILE];

    // per-M-tile constants (m in {0,1}): C/D rows 32w+16m+4lg+r, A rows 32w+16m+ln
    float a[2][4], ow[2][4];
    bf16x8 Ahh[2][2], Aix[2];
    int wbyte[2];
#pragma unroll
    for (int m = 0; m < 2; ++m) {
        const int jb   = 32 * wave + 16 * m + 4 * lg;
        const int arow = 32 * wave + 16 * m + ln;
#pragma unroll
        for (int r = 0; r < 4; ++r) {
            a[m][r]  = 1.0f - DTC / fabsf(tau[jb + r]);
            ow[m][r] = outw[jb + r];
        }
#pragma unroll
        for (int kt = 0; kt < 2; ++kt) {
            short8 s;
#pragma unroll
            for (int q = 0; q < 8; ++q)
                s[q] = (short)f2bf(DTC * Whh[arow * HID + kt * 32 + lg * 8 + q]);
            Ahh[m][kt] = __builtin_bit_cast(bf16x8, s);
        }
        short8 sx = {0,0,0,0,0,0,0,0};
        if (lg == 0) {
#pragma unroll
            for (int d = 0; d < DIN; ++d) sx[d] = (short)f2bf(DTC * Wih[arow * DIN + d]);
            sx[5] = (short)f2bf(DTC * (bih[arow] + bhh[arow]));
        }
        Aix[m] = __builtin_bit_cast(bf16x8, sx);
        // write slot (fragment-linear, verified formula): rows jb..jb+3, col ln
        wbyte[m] = ((jb >= 32) ? 1024 : 0) + (((jb & 31) >> 3) * 256)
                 + ln * 16 + (((jb >> 2) & 1) * 8);
    }

    const char* const rp0 = (const char*)sbuf[0] + lane * 16;
    const char* const rp1 = (const char*)sbuf[1] + lane * 16;

    // zero parity-1 buffer (read at t=0: tanh(h0)=0): 256 u64 over 128 threads
    ((u64*)sbuf[1])[tid]       = 0ULL;
    ((u64*)sbuf[1])[tid + 128] = 0ULL;

    // x: per-lane row, 8-step float4 groups (40 floats = 10 float4, 16B-aligned)
    const float* xb = x + (size_t)(b0 + ln) * (SEQ * DIN);
    f32x4 bufA[10], bufB[10];
#pragma unroll
    for (int i = 0; i < 10; ++i) bufA[i] = *(const f32x4*)(xb + 4 * i);  // steps 0..7

    f32x4 h[2];
#pragma unroll
    for (int m = 0; m < 2; ++m) { h[m][0]=0.f; h[m][1]=0.f; h[m][2]=0.f; h[m][3]=0.f; }

    // soft barrier: order LDS writes cross-wave; do NOT drain vmcnt
#define SBAR() asm volatile("s_waitcnt lgkmcnt(0)\n\ts_barrier" ::: "memory")

#define BODY(PAR, X0, X1, X2, X3, X4)                                              \
    {                                                                              \
        const char* rb = (PAR) ? rp0 : rp1;        /* read parity = !PAR */        \
        i32x4 r0 = *(const i32x4*)(rb);                                            \
        i32x4 r1 = *(const i32x4*)(rb + 1024);                                     \
        i32x4 bx;                                                                  \
        bx[0] = (int)cvt_pk_bf16(X0, X1);                                          \
        bx[1] = (int)cvt_pk_bf16(X2, X3);                                          \
        bx[2] = (int)cvt_pk_bf16(X4, 1.0f);                                        \
        bx[3] = 0;                                                                 \
        f32x4 c0, c1;                                                              \
        c0[0] = a[0][0]*h[0][0]; c0[1] = a[0][1]*h[0][1];                          \
        c0[2] = a[0][2]*h[0][2]; c0[3] = a[0][3]*h[0][3];                          \
        c1[0] = a[1][0]*h[1][0]; c1[1] = a[1][1]*h[1][1];                          \
        c1[2] = a[1][2]*h[1][2]; c1[3] = a[1][3]*h[1][3];                          \
        c0 = __builtin_amdgcn_mfma_f32_16x16x32_bf16(Aix[0], __builtin_bit_cast(bf16x8, bx), c0, 0, 0, 0); \
        c1 = __builtin_amdgcn_mfma_f32_16x16x32_bf16(Aix[1], __builtin_bit_cast(bf16x8, bx), c1, 0, 0, 0); \
        c0 = __builtin_amdgcn_mfma_f32_16x16x32_bf16(Ahh[0][0], __builtin_bit_cast(bf16x8, r0), c0, 0, 0, 0); \
        c1 = __builtin_amdgcn_mfma_f32_16x16x32_bf16(Ahh[1][0], __builtin_bit_cast(bf16x8, r0), c1, 0, 0, 0); \
        c0 = __builtin_amdgcn_mfma_f32_16x16x32_bf16(Ahh[0][1], __builtin_bit_cast(bf16x8, r1), c0, 0, 0, 0); \
        c1 = __builtin_amdgcn_mfma_f32_16x16x32_bf16(Ahh[1][1], __builtin_bit_cast(bf16x8, r1), c1, 0, 0, 0); \
        h[0] = c0; h[1] = c1;                                                      \
        float t00 = fast_tanh(c0[0]), t01 = fast_tanh(c0[1]);                      \
        float t02 = fast_tanh(c0[2]), t03 = fast_tanh(c0[3]);                      \
        float t10 = fast_tanh(c1[0]), t11 = fast_tanh(c1[1]);                      \
        float t12 = fast_tanh(c1[2]), t13 = fast_tanh(c1[3]);                      \
        char* wb = (char*)sbuf[(PAR)];                                             \
        i32x2 w0; w0[0] = (int)cvt_pk_bf16(t00, t01); w0[1] = (int)cvt_pk_bf16(t02, t03); \
        i32x2 w1; w1[0] = (int)cvt_pk_bf16(t10, t11); w1[1] = (int)cvt_pk_bf16(t12, t13); \
        *(i32x2*)(wb + wbyte[0]) = w0;                                             \
        *(i32x2*)(wb + wbyte[1]) = w1;                                             \
    }

    // 8 steps per superstep; x-floats for step s are elements [5s..5s+4]
#define SUPER(BUF, DO_LOAD, LBUF, LOFF)                                            \
    SBAR();                                                                        \
    if (DO_LOAD) {                                                                 \
        _Pragma("unroll")                                                          \
        for (int i = 0; i < 10; ++i) LBUF[i] = *(const f32x4*)(xb + (LOFF) + 4*i); \
    }                                                                              \
    BODY(0, BUF[0][0], BUF[0][1], BUF[0][2], BUF[0][3], BUF[1][0])                 \
    SBAR(); BODY(1, BUF[1][1], BUF[1][2], BUF[1][3], BUF[2][0], BUF[2][1])         \
    SBAR(); BODY(0, BUF[2][2], BUF[2][3], BUF[3][0], BUF[3][1], BUF[3][2])         \
    SBAR(); BODY(1, BUF[3][3], BUF[4][0], BUF[4][1], BUF[4][2], BUF[4][3])         \
    SBAR(); BODY(0, BUF[5][0], BUF[5][1], BUF[5][2], BUF[5][3], BUF[6][0])         \
    SBAR(); BODY(1, BUF[6][1], BUF[6][2], BUF[6][3], BUF[7][0], BUF[7][1])         \
    SBAR(); BODY(0, BUF[7][2], BUF[7][3], BUF[8][0], BUF[8][1], BUF[8][2])         \
    SBAR(); BODY(1, BUF[8][3], BUF[9][0], BUF[9][1], BUF[9][2], BUF[9][3])

    for (int it = 0; it < SEQ / 16; ++it) {
        SUPER(bufA, true,            bufB, (it * 16 + 8)  * DIN)   // steps 16it..+7
        SUPER(bufB, it != SEQ/16 - 1, bufA, (it * 16 + 16) * DIN)  // steps 16it+8..+15
    }
#undef SUPER
#undef BODY
#undef SBAR

    // epilogue: out[b] = tanh(h_final) . out_w + out_b
    float part = 0.0f;
#pragma unroll
    for (int m = 0; m < 2; ++m)
#pragma unroll
        for (int r = 0; r < 4; ++r)
            part += fast_tanh(h[m][r]) * ow[m][r];
    redbuf[wave][lg][ln] = part;
    __syncthreads();
    if (tid < BTILE) {
        float s = outb[0];
#pragma unroll
        for (int w = 0; w < NWAVE; ++w)
#pragma unroll
            for (int g = 0; g < 4; ++g) s += redbuf[w][g][tid];
        out[b0 + tid] = s;
    }
}

extern "C" void kernel_launch(void* const* d_in, const int* in_sizes, int n_in,
                              void* d_out, int out_size, void* d_ws, size_t ws_size,
                              hipStream_t stream) {
    const float* x    = (const float*)d_in[0];
    const float* tau  = (const float*)d_in[1];
    const float* Wih  = (const float*)d_in[2];
    const float* bih  = (const float*)d_in[3];
    const float* Whh  = (const float*)d_in[4];
    const float* bhh  = (const float*)d_in[5];
    const float* outw = (const float*)d_in[6];
    const float* outb = (const float*)d_in[7];
    float* out = (float*)d_out;

    const int batch = in_sizes[0] / (SEQ * DIN);   // 4096
    ltc_kernel<<<batch / BTILE, NWAVE * 64, 0, stream>>>(x, tau, Wih, bih, Whh, bhh, outw, outb, out);
}